// Round 1
// baseline (677.310 us; speedup 1.0000x reference)
//
#include <hip/hip_runtime.h>

#define VGRID 64
#define NUM_VOXELS (VGRID * VGRID * VGRID)   // 262144
#define NCH 64                               // channels == wave width

// ---------------------------------------------------------------------------
// Kernel 1: init feats to -inf, count to 0, write voxel_coors (fn of index).
// Grid covers V*C elements; first V threads also handle count/coors.
// ---------------------------------------------------------------------------
__global__ void init_kernel(unsigned int* __restrict__ feats_bits,
                            float* __restrict__ vcoors,
                            float* __restrict__ count) {
    int i = blockIdx.x * blockDim.x + threadIdx.x;
    if (i < NUM_VOXELS * NCH) {
        feats_bits[i] = 0xFF800000u;  // -inf
    }
    if (i < NUM_VOXELS) {
        count[i] = 0.0f;
        vcoors[i * 3 + 0] = (float)(i >> 12);        // x = vid / 4096
        vcoors[i * 3 + 1] = (float)((i >> 6) & 63);  // y = (vid / 64) % 64
        vcoors[i * 3 + 2] = (float)(i & 63);         // z = vid % 64
    }
}

// ---------------------------------------------------------------------------
// Kernel 2: one wave (64 lanes) per point; lane == channel.
// Float atomic max via signed-max (v>=0) / unsigned-min (v<0) bit trick.
// Monotone non-decreasing in float order under any interleaving; init -inf.
// ---------------------------------------------------------------------------
__global__ void scatter_kernel(const float* __restrict__ points,
                               const int* __restrict__ coors,
                               float* __restrict__ feats,
                               float* __restrict__ count,
                               int n_points) {
    int gid = blockIdx.x * blockDim.x + threadIdx.x;
    int p = gid >> 6;     // point index: one wave per point
    int lane = gid & 63;  // channel index
    if (p >= n_points) return;

    int seg = 0;
    if (lane == 0) {
        int x = coors[p * 3 + 0];
        int y = coors[p * 3 + 1];
        int z = coors[p * 3 + 2];
        seg = (x * VGRID + y) * VGRID + z;
    }
    seg = __shfl(seg, 0, 64);  // broadcast voxel id to all 64 lanes

    float v = points[(size_t)p * NCH + lane];  // fully coalesced 256B/wave
    float* addr = feats + (size_t)seg * NCH + lane;
    if (v >= 0.0f) {
        atomicMax((int*)addr, __float_as_int(v));
    } else {
        atomicMin((unsigned int*)addr, __float_as_uint(v));
    }
    if (lane == 0) {
        atomicAdd(count + seg, 1.0f);  // exact for integer counts << 2^24
    }
}

// ---------------------------------------------------------------------------
// Kernel 3: zero out empty voxels (count==0). Each wave covers exactly one
// voxel (i>>6 uniform across wave) -> count load is one broadcast transaction.
// Occupied voxels had every channel touched by >=1 atomic, so no -inf remains.
// ---------------------------------------------------------------------------
__global__ void finalize_kernel(float* __restrict__ feats,
                                const float* __restrict__ count) {
    int i = blockIdx.x * blockDim.x + threadIdx.x;
    if (i >= NUM_VOXELS * NCH) return;
    int v = i >> 6;
    if (count[v] == 0.0f) feats[i] = 0.0f;
}

extern "C" void kernel_launch(void* const* d_in, const int* in_sizes, int n_in,
                              void* d_out, int out_size, void* d_ws, size_t ws_size,
                              hipStream_t stream) {
    const float* points = (const float*)d_in[0];
    const int* coors = (const int*)d_in[1];
    const int n_points = in_sizes[0] / NCH;  // 1,000,000

    // Output layout: [feats V*64 | vcoors V*3 | count V], all float32.
    float* feats = (float*)d_out;
    float* vcoors = feats + (size_t)NUM_VOXELS * NCH;
    float* count = vcoors + (size_t)NUM_VOXELS * 3;

    const int total_vc = NUM_VOXELS * NCH;  // 16,777,216
    init_kernel<<<(total_vc + 255) / 256, 256, 0, stream>>>(
        (unsigned int*)feats, vcoors, count);

    const int total_pc = n_points * NCH;  // 64,000,000
    scatter_kernel<<<(total_pc + 255) / 256, 256, 0, stream>>>(
        points, coors, feats, count, n_points);

    finalize_kernel<<<(total_vc + 255) / 256, 256, 0, stream>>>(feats, count);
}

// Round 2
// 582.696 us; speedup vs baseline: 1.1624x; 1.1624x over previous
//
#include <hip/hip_runtime.h>

#define VGRID 64
#define NUM_VOXELS (VGRID * VGRID * VGRID)   // 262144
#define NCH 64                               // channels == wave width
#define NPTS 1000000

// ws layout (ints): seg[N] | cnt[V] | offs[V] | cursor[V] | blocksum[1024] | blockpref[1024] | point_ids[N]
// total = 2N + 3V + 2048 ints ~= 11.2 MB

// --------------------------------------------------------------------------
// K0: zero the per-voxel counters (ws is poisoned 0xAA before every call).
// --------------------------------------------------------------------------
__global__ void zero_cnt_kernel(int* __restrict__ cnt) {
    int i = blockIdx.x * blockDim.x + threadIdx.x;
    if (i < NUM_VOXELS) cnt[i] = 0;
}

// --------------------------------------------------------------------------
// K1: per point, compute linear voxel id, histogram into cnt (L2-resident).
// --------------------------------------------------------------------------
__global__ void seg_count_kernel(const int* __restrict__ coors,
                                 int* __restrict__ seg,
                                 int* __restrict__ cnt,
                                 int n_points) {
    int p = blockIdx.x * blockDim.x + threadIdx.x;
    if (p >= n_points) return;
    int x = coors[p * 3 + 0];
    int y = coors[p * 3 + 1];
    int z = coors[p * 3 + 2];
    int s = (x * VGRID + y) * VGRID + z;
    seg[p] = s;
    atomicAdd(cnt + s, 1);
}

// --------------------------------------------------------------------------
// K2: per-256-block inclusive scan of cnt -> exclusive offs + block totals.
// --------------------------------------------------------------------------
__global__ void scan_blocks_kernel(const int* __restrict__ cnt,
                                   int* __restrict__ offs,
                                   int* __restrict__ blocksum) {
    __shared__ int s[256];
    int tid = threadIdx.x;
    int g = blockIdx.x * 256 + tid;
    int x = cnt[g];
    s[tid] = x;
    __syncthreads();
    for (int off = 1; off < 256; off <<= 1) {
        int t = (tid >= off) ? s[tid - off] : 0;
        __syncthreads();
        s[tid] += t;
        __syncthreads();
    }
    offs[g] = s[tid] - x;  // exclusive within block
    if (tid == 255) blocksum[blockIdx.x] = s[255];
}

// --------------------------------------------------------------------------
// K3: single-block exclusive scan of the 1024 block sums.
// --------------------------------------------------------------------------
__global__ void scan_top_kernel(const int* __restrict__ blocksum,
                                int* __restrict__ blockpref) {
    __shared__ int s[1024];
    int tid = threadIdx.x;
    int x = blocksum[tid];
    s[tid] = x;
    __syncthreads();
    for (int off = 1; off < 1024; off <<= 1) {
        int t = (tid >= off) ? s[tid - off] : 0;
        __syncthreads();
        s[tid] += t;
        __syncthreads();
    }
    blockpref[tid] = s[tid] - x;  // exclusive
}

// --------------------------------------------------------------------------
// K4: finalize offsets, seed cursors, and write count + voxel_coors outputs.
// --------------------------------------------------------------------------
__global__ void finalize_offsets_kernel(int* __restrict__ offs,
                                        const int* __restrict__ blockpref,
                                        int* __restrict__ cursor,
                                        const int* __restrict__ cnt,
                                        float* __restrict__ count_out,
                                        float* __restrict__ vcoors) {
    int g = blockIdx.x * blockDim.x + threadIdx.x;
    if (g >= NUM_VOXELS) return;
    int o = offs[g] + blockpref[g >> 8];
    offs[g] = o;
    cursor[g] = o;
    count_out[g] = (float)cnt[g];
    vcoors[g * 3 + 0] = (float)(g >> 12);
    vcoors[g * 3 + 1] = (float)((g >> 6) & 63);
    vcoors[g * 3 + 2] = (float)(g & 63);
}

// --------------------------------------------------------------------------
// K5: bucket-fill point ids (order within bucket irrelevant for max).
// --------------------------------------------------------------------------
__global__ void bucket_fill_kernel(const int* __restrict__ seg,
                                   int* __restrict__ cursor,
                                   int* __restrict__ point_ids,
                                   int n_points) {
    int p = blockIdx.x * blockDim.x + threadIdx.x;
    if (p >= n_points) return;
    int s = seg[p];
    int slot = atomicAdd(cursor + s, 1);
    point_ids[slot] = p;
}

// --------------------------------------------------------------------------
// K6: one wave per voxel, lane == channel. Reduce max over bucket points in
// registers; single coalesced 256B row store per voxel (0 if empty).
// --------------------------------------------------------------------------
__global__ void gather_max_kernel(const float* __restrict__ points,
                                  const int* __restrict__ offs,
                                  const int* __restrict__ cnt,
                                  const int* __restrict__ point_ids,
                                  float* __restrict__ feats) {
    int gid = blockIdx.x * blockDim.x + threadIdx.x;
    int v = gid >> 6;     // voxel id (uniform per wave)
    int lane = gid & 63;  // channel
    if (v >= NUM_VOXELS) return;

    int n = cnt[v];       // broadcast load (same addr across wave)
    int start = offs[v];
    float acc = -__builtin_inf();
    for (int j = 0; j < n; ++j) {
        int p = point_ids[start + j];                    // broadcast load
        acc = fmaxf(acc, points[(size_t)p * NCH + lane]); // 256B coalesced
    }
    feats[(size_t)v * NCH + lane] = (n > 0) ? acc : 0.0f;
}

extern "C" void kernel_launch(void* const* d_in, const int* in_sizes, int n_in,
                              void* d_out, int out_size, void* d_ws, size_t ws_size,
                              hipStream_t stream) {
    const float* points = (const float*)d_in[0];
    const int* coors = (const int*)d_in[1];
    const int n_points = in_sizes[0] / NCH;  // 1,000,000

    // Output layout: [feats V*64 | vcoors V*3 | count V], all float32.
    float* feats = (float*)d_out;
    float* vcoors = feats + (size_t)NUM_VOXELS * NCH;
    float* count_out = vcoors + (size_t)NUM_VOXELS * 3;

    // Workspace carve-up (ints).
    int* w = (int*)d_ws;
    int* seg = w;                    // N
    int* cnt = seg + NPTS;           // V
    int* offs = cnt + NUM_VOXELS;    // V
    int* cursor = offs + NUM_VOXELS; // V
    int* blocksum = cursor + NUM_VOXELS;  // 1024
    int* blockpref = blocksum + 1024;     // 1024
    int* point_ids = blockpref + 1024;    // N

    zero_cnt_kernel<<<NUM_VOXELS / 256, 256, 0, stream>>>(cnt);

    seg_count_kernel<<<(n_points + 255) / 256, 256, 0, stream>>>(
        coors, seg, cnt, n_points);

    scan_blocks_kernel<<<NUM_VOXELS / 256, 256, 0, stream>>>(
        cnt, offs, blocksum);

    scan_top_kernel<<<1, 1024, 0, stream>>>(blocksum, blockpref);

    finalize_offsets_kernel<<<NUM_VOXELS / 256, 256, 0, stream>>>(
        offs, blockpref, cursor, cnt, count_out, vcoors);

    bucket_fill_kernel<<<(n_points + 255) / 256, 256, 0, stream>>>(
        seg, cursor, point_ids, n_points);

    const int total_vc = NUM_VOXELS * NCH;  // 16,777,216 threads
    gather_max_kernel<<<total_vc / 256, 256, 0, stream>>>(
        points, offs, cnt, point_ids, feats);
}

// Round 3
// 545.145 us; speedup vs baseline: 1.2424x; 1.0689x over previous
//
#include <hip/hip_runtime.h>

#define VGRID 64
#define NUM_VOXELS (VGRID * VGRID * VGRID)   // 262144
#define NCH 64                               // channels == wave width
#define NPTS 1000000

// ws layout (ints): seg[N] | cnt[V] | offs[V] | cursor[V] | blocksum[1024] | blockpref[1024] | point_ids[N]

// --------------------------------------------------------------------------
// K0: zero the per-voxel counters (ws is poisoned 0xAA before every call).
// --------------------------------------------------------------------------
__global__ void zero_cnt_kernel(int* __restrict__ cnt) {
    int i = blockIdx.x * blockDim.x + threadIdx.x;
    if (i < NUM_VOXELS) cnt[i] = 0;
}

// --------------------------------------------------------------------------
// K1: per point, compute linear voxel id, histogram into cnt (L2-resident).
// --------------------------------------------------------------------------
__global__ void seg_count_kernel(const int* __restrict__ coors,
                                 int* __restrict__ seg,
                                 int* __restrict__ cnt,
                                 int n_points) {
    int p = blockIdx.x * blockDim.x + threadIdx.x;
    if (p >= n_points) return;
    int x = coors[p * 3 + 0];
    int y = coors[p * 3 + 1];
    int z = coors[p * 3 + 2];
    int s = (x * VGRID + y) * VGRID + z;
    seg[p] = s;
    atomicAdd(cnt + s, 1);
}

// --------------------------------------------------------------------------
// K2: per-256-block inclusive scan of cnt -> exclusive offs + block totals.
// --------------------------------------------------------------------------
__global__ void scan_blocks_kernel(const int* __restrict__ cnt,
                                   int* __restrict__ offs,
                                   int* __restrict__ blocksum) {
    __shared__ int s[256];
    int tid = threadIdx.x;
    int g = blockIdx.x * 256 + tid;
    int x = cnt[g];
    s[tid] = x;
    __syncthreads();
    for (int off = 1; off < 256; off <<= 1) {
        int t = (tid >= off) ? s[tid - off] : 0;
        __syncthreads();
        s[tid] += t;
        __syncthreads();
    }
    offs[g] = s[tid] - x;  // exclusive within block
    if (tid == 255) blocksum[blockIdx.x] = s[255];
}

// --------------------------------------------------------------------------
// K3: single-block exclusive scan of the 1024 block sums.
// --------------------------------------------------------------------------
__global__ void scan_top_kernel(const int* __restrict__ blocksum,
                                int* __restrict__ blockpref) {
    __shared__ int s[1024];
    int tid = threadIdx.x;
    int x = blocksum[tid];
    s[tid] = x;
    __syncthreads();
    for (int off = 1; off < 1024; off <<= 1) {
        int t = (tid >= off) ? s[tid - off] : 0;
        __syncthreads();
        s[tid] += t;
        __syncthreads();
    }
    blockpref[tid] = s[tid] - x;  // exclusive
}

// --------------------------------------------------------------------------
// K4: finalize offsets, seed cursors, and write count + voxel_coors outputs.
// --------------------------------------------------------------------------
__global__ void finalize_offsets_kernel(int* __restrict__ offs,
                                        const int* __restrict__ blockpref,
                                        int* __restrict__ cursor,
                                        const int* __restrict__ cnt,
                                        float* __restrict__ count_out,
                                        float* __restrict__ vcoors) {
    int g = blockIdx.x * blockDim.x + threadIdx.x;
    if (g >= NUM_VOXELS) return;
    int o = offs[g] + blockpref[g >> 8];
    offs[g] = o;
    cursor[g] = o;
    count_out[g] = (float)cnt[g];
    vcoors[g * 3 + 0] = (float)(g >> 12);
    vcoors[g * 3 + 1] = (float)((g >> 6) & 63);
    vcoors[g * 3 + 2] = (float)(g & 63);
}

// --------------------------------------------------------------------------
// K5: bucket-fill point ids (order within bucket irrelevant for max).
// --------------------------------------------------------------------------
__global__ void bucket_fill_kernel(const int* __restrict__ seg,
                                   int* __restrict__ cursor,
                                   int* __restrict__ point_ids,
                                   int n_points) {
    int p = blockIdx.x * blockDim.x + threadIdx.x;
    if (p >= n_points) return;
    int s = seg[p];
    int slot = atomicAdd(cursor + s, 1);
    point_ids[slot] = p;
}

// --------------------------------------------------------------------------
// K6: one wave per voxel. Lane l handles point-row-group (l>>4) and channels
// [4*(l&15), 4*(l&15)+3]. One global_load_dwordx4 per wave covers 4 point
// rows (1 KiB). All bucket ids prefetched in one predicated vector load and
// distributed via shfl — no serialized broadcast-load chain. Clamped
// duplicate rows are harmless (max is idempotent).
// --------------------------------------------------------------------------
__global__ void gather_max_kernel(const float* __restrict__ points,
                                  const int* __restrict__ offs,
                                  const int* __restrict__ cnt,
                                  const int* __restrict__ point_ids,
                                  float* __restrict__ feats) {
    int gid = blockIdx.x * blockDim.x + threadIdx.x;
    int v = gid >> 6;     // voxel id (uniform per wave)
    int lane = gid & 63;
    if (v >= NUM_VOXELS) return;

    int n = cnt[v];       // broadcast load
    int start = offs[v];
    int grp = lane >> 4;      // which of 4 rows this lane loads
    int q = lane & 15;        // float4 column within the row

    const float4* pts4 = (const float4*)points;
    float4 acc = make_float4(-__builtin_inff(), -__builtin_inff(),
                             -__builtin_inff(), -__builtin_inff());

    for (int b0 = 0; b0 < n; b0 += 64) {
        int m = min(n - b0, 64);
        // one vector load fetches up to 64 bucket ids
        int my_id = (lane < m) ? point_ids[start + b0 + lane] : 0;
        for (int r = 0; r < m; r += 4) {
            int src = min(r + grp, m - 1);       // clamp: dup rows are no-ops
            int p = __shfl(my_id, src, 64);
            float4 val = pts4[(size_t)p * 16 + q];
            acc.x = fmaxf(acc.x, val.x);
            acc.y = fmaxf(acc.y, val.y);
            acc.z = fmaxf(acc.z, val.z);
            acc.w = fmaxf(acc.w, val.w);
        }
    }

    // combine the 4 row-groups: xor-16 then xor-32
    #pragma unroll
    for (int mask = 16; mask <= 32; mask <<= 1) {
        acc.x = fmaxf(acc.x, __shfl_xor(acc.x, mask, 64));
        acc.y = fmaxf(acc.y, __shfl_xor(acc.y, mask, 64));
        acc.z = fmaxf(acc.z, __shfl_xor(acc.z, mask, 64));
        acc.w = fmaxf(acc.w, __shfl_xor(acc.w, mask, 64));
    }

    if (lane < 16) {
        float4 out = (n > 0) ? acc : make_float4(0.f, 0.f, 0.f, 0.f);
        ((float4*)feats)[(size_t)v * 16 + lane] = out;
    }
}

extern "C" void kernel_launch(void* const* d_in, const int* in_sizes, int n_in,
                              void* d_out, int out_size, void* d_ws, size_t ws_size,
                              hipStream_t stream) {
    const float* points = (const float*)d_in[0];
    const int* coors = (const int*)d_in[1];
    const int n_points = in_sizes[0] / NCH;  // 1,000,000

    // Output layout: [feats V*64 | vcoors V*3 | count V], all float32.
    float* feats = (float*)d_out;
    float* vcoors = feats + (size_t)NUM_VOXELS * NCH;
    float* count_out = vcoors + (size_t)NUM_VOXELS * 3;

    // Workspace carve-up (ints).
    int* w = (int*)d_ws;
    int* seg = w;                    // N
    int* cnt = seg + NPTS;           // V
    int* offs = cnt + NUM_VOXELS;    // V
    int* cursor = offs + NUM_VOXELS; // V
    int* blocksum = cursor + NUM_VOXELS;  // 1024
    int* blockpref = blocksum + 1024;     // 1024
    int* point_ids = blockpref + 1024;    // N

    zero_cnt_kernel<<<NUM_VOXELS / 256, 256, 0, stream>>>(cnt);

    seg_count_kernel<<<(n_points + 255) / 256, 256, 0, stream>>>(
        coors, seg, cnt, n_points);

    scan_blocks_kernel<<<NUM_VOXELS / 256, 256, 0, stream>>>(
        cnt, offs, blocksum);

    scan_top_kernel<<<1, 1024, 0, stream>>>(blocksum, blockpref);

    finalize_offsets_kernel<<<NUM_VOXELS / 256, 256, 0, stream>>>(
        offs, blockpref, cursor, cnt, count_out, vcoors);

    bucket_fill_kernel<<<(n_points + 255) / 256, 256, 0, stream>>>(
        seg, cursor, point_ids, n_points);

    const int total_vc = NUM_VOXELS * NCH;  // 16,777,216 threads
    gather_max_kernel<<<total_vc / 256, 256, 0, stream>>>(
        points, offs, cnt, point_ids, feats);
}